// Round 4
// baseline (239.946 us; speedup 1.0000x reference)
//
#include <hip/hip_runtime.h>

#define BB 4
#define NN 16384
#define EE 65536
#define CC 256
#define MM 64

// ws float offsets
#define WS_NORM   0                  // B*M (atomics, memset each launch)
#define WS_T1     256
#define WS_ESN    512
#define WS_BCOMB  768                // 64
#define WS_ITX    832                // 64
#define WS_ITE    896                // 64
#define WS_WES2   1024               // 64*64 = 4096  (itE ⊙ W_eslice)
#define WS_WCOMB  5120               // C*M = 16384
#define WS_SW2    21504              // B*N*M = 4194304
#define WS_SPART  4215808            // B*PB*M*C partials

// ---------- P: W_comb = W_x @ W_slice ----------
__global__ __launch_bounds__(256) void kP(const float* __restrict__ Wx,
                                          const float* __restrict__ Wsl,
                                          float* __restrict__ ws) {
    int e = blockIdx.x * 256 + threadIdx.x;   // 16384 entries
    int c = e >> 6, m = e & 63;
    float acc = 0.f;
    for (int k = 0; k < CC; ++k) acc += Wx[c * CC + k] * Wsl[k * MM + m];
    ws[WS_WCOMB + e] = acc;
}

// ---------- P2: b_comb, inverse temps, Wes2 = itE ⊙ Wes ----------
__global__ void kP2(const float* __restrict__ bx, const float* __restrict__ phx,
                    const float* __restrict__ Wsl, const float* __restrict__ bsl,
                    const float* __restrict__ tx, const float* __restrict__ te,
                    const float* __restrict__ Wes,
                    float* __restrict__ ws) {
    int m = threadIdx.x; // 64 threads
    float acc = bsl[m];
    for (int k = 0; k < CC; ++k) acc += (bx[k] + phx[k]) * Wsl[k * MM + m];
    ws[WS_BCOMB + m] = acc;
    ws[WS_ITX + m] = 1.f / fminf(fmaxf(tx[m], 0.01f), 5.f);
    ws[WS_ITE + m] = 1.f / fminf(fmaxf(te[m], 0.01f), 5.f);
    for (int k = 0; k < 64; ++k) {
        float itk = 1.f / fminf(fmaxf(te[k], 0.01f), 5.f);
        ws[WS_WES2 + k * 64 + m] = itk * Wes[k * 64 + m];
    }
}

// ---------- N1: logits = x@W_comb + b_comb, softmax -> slice_weight + norm ----------
// 256 blocks x 256 threads; 256 rows/block; thread owns 4 rows x 16 m.
// __launch_bounds__(256, 1): allow full VGPR budget — acc[4][16] + prefetch
// regs need ~115 VGPRs; default cap (72) caused 70MB of scratch spill (r3).
__global__ __launch_bounds__(256, 1) void kN1(const float* __restrict__ x,
                                              const float* __restrict__ ws,
                                              float* __restrict__ out1,
                                              float* __restrict__ norm_acc) {
    __shared__ float xs[256 * 36];   // 36 KB, row stride 36 (2-way conflicts = free)
    __shared__ float Wst[32 * 64];   // 8 KB  (one 32-row chunk of W_comb)
    __shared__ float redn[4][64];
    __shared__ float bcs[64], itxs[64];
    const int tid = threadIdx.x;
    const int row0 = blockIdx.x * 256;
    const int b = blockIdx.x >> 6;   // 64 blocks per batch
    const int r = tid >> 2;          // 0..63
    const int h = tid & 3;           // m-quarter
    const float* Wc = ws + WS_WCOMB;

    if (tid < 64) { bcs[tid] = ws[WS_BCOMB + tid]; itxs[tid] = ws[WS_ITX + tid]; }

    float4 xr[8], wr[2];
#pragma unroll
    for (int i = 0; i < 8; ++i) {
        int flat = i * 256 + tid, rr = flat >> 3, cb = (flat & 7) * 4;
        xr[i] = *(const float4*)(x + (size_t)(row0 + rr) * CC + cb);
    }
#pragma unroll
    for (int i = 0; i < 2; ++i) {
        int f4 = i * 256 + tid;
        wr[i] = *(const float4*)(Wc + f4 * 4);
    }

    float acc[4][16];
#pragma unroll
    for (int i = 0; i < 4; ++i)
#pragma unroll
        for (int j = 0; j < 16; ++j) acc[i][j] = 0.f;

    for (int c0 = 0; c0 < CC; c0 += 32) {
        // write prefetched chunk to LDS
#pragma unroll
        for (int i = 0; i < 8; ++i) {
            int flat = i * 256 + tid, rr = flat >> 3, cb = (flat & 7) * 4;
            *(float4*)&xs[rr * 36 + cb] = xr[i];
        }
#pragma unroll
        for (int i = 0; i < 2; ++i) {
            int f4 = i * 256 + tid;
            *(float4*)&Wst[f4 * 4] = wr[i];
        }
        __syncthreads();
        // prefetch next chunk (hidden under compute)
        if (c0 < CC - 32) {
#pragma unroll
            for (int i = 0; i < 8; ++i) {
                int flat = i * 256 + tid, rr = flat >> 3, cb = (flat & 7) * 4;
                xr[i] = *(const float4*)(x + (size_t)(row0 + rr) * CC + (c0 + 32) + cb);
            }
#pragma unroll
            for (int i = 0; i < 2; ++i) {
                int f4 = i * 256 + tid;
                wr[i] = *(const float4*)(Wc + (c0 + 32) * MM + f4 * 4);
            }
        }
#pragma unroll 4
        for (int cc = 0; cc < 32; ++cc) {
            float xv0 = xs[(r      ) * 36 + cc];
            float xv1 = xs[(r +  64) * 36 + cc];
            float xv2 = xs[(r + 128) * 36 + cc];
            float xv3 = xs[(r + 192) * 36 + cc];
            const float4* wrow = (const float4*)&Wst[cc * 64 + h * 16];
#pragma unroll
            for (int q = 0; q < 4; ++q) {
                float4 w = wrow[q];
                acc[0][q * 4 + 0] += xv0 * w.x; acc[0][q * 4 + 1] += xv0 * w.y;
                acc[0][q * 4 + 2] += xv0 * w.z; acc[0][q * 4 + 3] += xv0 * w.w;
                acc[1][q * 4 + 0] += xv1 * w.x; acc[1][q * 4 + 1] += xv1 * w.y;
                acc[1][q * 4 + 2] += xv1 * w.z; acc[1][q * 4 + 3] += xv1 * w.w;
                acc[2][q * 4 + 0] += xv2 * w.x; acc[2][q * 4 + 1] += xv2 * w.y;
                acc[2][q * 4 + 2] += xv2 * w.z; acc[2][q * 4 + 3] += xv2 * w.w;
                acc[3][q * 4 + 0] += xv3 * w.x; acc[3][q * 4 + 1] += xv3 * w.y;
                acc[3][q * 4 + 2] += xv3 * w.z; acc[3][q * 4 + 3] += xv3 * w.w;
            }
        }
        __syncthreads();
    }

    // softmax per row (quad h=0..3 shares each row)
    float colsum[16];
#pragma unroll
    for (int j = 0; j < 16; ++j) colsum[j] = 0.f;
#pragma unroll
    for (int i = 0; i < 4; ++i) {
        float mx = -1e30f;
#pragma unroll
        for (int j = 0; j < 16; ++j) {
            int m = h * 16 + j;
            acc[i][j] = (acc[i][j] + bcs[m]) * itxs[m];
            mx = fmaxf(mx, acc[i][j]);
        }
        mx = fmaxf(mx, __shfl_xor(mx, 1));
        mx = fmaxf(mx, __shfl_xor(mx, 2));
        float s = 0.f;
#pragma unroll
        for (int j = 0; j < 16; ++j) { acc[i][j] = __expf(acc[i][j] - mx); s += acc[i][j]; }
        s += __shfl_xor(s, 1);
        s += __shfl_xor(s, 2);
        float inv = 1.f / s;
        int row = row0 + r + 64 * i;
#pragma unroll
        for (int q = 0; q < 4; ++q) {
            float4 v = {acc[i][q * 4 + 0] * inv, acc[i][q * 4 + 1] * inv,
                        acc[i][q * 4 + 2] * inv, acc[i][q * 4 + 3] * inv};
            *(float4*)(out1 + (size_t)row * MM + h * 16 + q * 4) = v;
#pragma unroll
            for (int j = 0; j < 4; ++j) colsum[q * 4 + j] += ((float*)&v)[j];
        }
    }
    // reduce colsum across the 16 r-lanes of each wave
#pragma unroll
    for (int j = 0; j < 16; ++j) {
        colsum[j] += __shfl_xor(colsum[j], 4);
        colsum[j] += __shfl_xor(colsum[j], 8);
        colsum[j] += __shfl_xor(colsum[j], 16);
        colsum[j] += __shfl_xor(colsum[j], 32);
    }
    int w = tid >> 6;
    if ((tid & 63) < 4) {
#pragma unroll
        for (int j = 0; j < 16; ++j) redn[w][h * 16 + j] = colsum[j];
    }
    __syncthreads();
    if (tid < 64)
        atomicAdd(&norm_acc[b * MM + tid],
                  redn[0][tid] + redn[1][tid] + redn[2][tid] + redn[3][tid]);
}

// ---------- N3: SW2 = sw @ Wes2  ([B*N,64]@[64,64]) ----------
__global__ __launch_bounds__(256, 1) void kN3(const float* __restrict__ sw,
                                              const float* __restrict__ ws,
                                              float* __restrict__ sw2) {
    __shared__ float Wst[64 * 64]; // 16 KB
    const int tid = threadIdx.x;
    const int r = tid >> 1, h = tid & 1;
    const size_t row = (size_t)blockIdx.x * 128 + r;
#pragma unroll
    for (int i = 0; i < 4; ++i) {
        int f4 = i * 256 + tid;
        *(float4*)&Wst[f4 * 4] = *(const float4*)(ws + WS_WES2 + f4 * 4);
    }
    float u[64];
    const float4* rp = (const float4*)(sw + row * MM);
#pragma unroll
    for (int q = 0; q < 16; ++q) {
        float4 a = rp[q];
        u[q * 4 + 0] = a.x; u[q * 4 + 1] = a.y; u[q * 4 + 2] = a.z; u[q * 4 + 3] = a.w;
    }
    float acc[32];
#pragma unroll
    for (int j = 0; j < 32; ++j) acc[j] = 0.f;
    __syncthreads();
#pragma unroll
    for (int k = 0; k < 64; ++k) {
        float uk = u[k];
        const float4* wr4 = (const float4*)&Wst[k * 64 + h * 32];
#pragma unroll
        for (int q = 0; q < 8; ++q) {
            float4 wv = wr4[q];
            acc[q * 4 + 0] += uk * wv.x; acc[q * 4 + 1] += uk * wv.y;
            acc[q * 4 + 2] += uk * wv.z; acc[q * 4 + 3] += uk * wv.w;
        }
    }
#pragma unroll
    for (int q = 0; q < 8; ++q) {
        float4 v = {acc[q * 4 + 0], acc[q * 4 + 1], acc[q * 4 + 2], acc[q * 4 + 3]};
        *(float4*)(sw2 + row * MM + h * 32 + q * 4) = v;
    }
}

// ---------- N2: Spart[b][p] = sw_chunk^T @ x_chunk (register-tiled) ----------
__global__ __launch_bounds__(256, 1) void kN2(const float* __restrict__ x,
                                              const float* __restrict__ sw,
                                              float* __restrict__ Spart,
                                              int PB, int rowsPB) {
    __shared__ float xs[32][288];   // 36 KB, col j stored at j + (j>>5)*4
    __shared__ float sws[32][64];   // 8 KB
    const int bid = blockIdx.x;
    const int b = bid / PB, p = bid % PB;
    const int base = b * NN + p * rowsPB;
    const int tid = threadIdx.x;
    const int tm = tid >> 4, tc = tid & 15;
    const int m0 = tm * 4, c0 = tc * 16;

    float acc[4][16];
#pragma unroll
    for (int mi = 0; mi < 4; ++mi)
#pragma unroll
        for (int j = 0; j < 16; ++j) acc[mi][j] = 0.f;

    for (int r0 = 0; r0 < rowsPB; r0 += 32) {
        __syncthreads();
#pragma unroll
        for (int i = 0; i < 8; ++i) {
            int flat = i * 256 + tid;
            int r = flat >> 6, c = (flat & 63) * 4;
            float4 v = *(const float4*)(x + (size_t)(base + r0 + r) * CC + c);
            *(float4*)&xs[r][c + ((c >> 5) << 2)] = v;
        }
#pragma unroll
        for (int i = 0; i < 2; ++i) {
            int flat = i * 256 + tid;
            int r = flat >> 4, c = (flat & 15) * 4;
            *(float4*)&sws[r][c] = *(const float4*)(sw + (size_t)(base + r0 + r) * MM + c);
        }
        __syncthreads();
#pragma unroll 2
        for (int r = 0; r < 32; ++r) {
            float4 s4 = *(float4*)&sws[r][m0];
#pragma unroll
            for (int q = 0; q < 4; ++q) {
                int c = c0 + q * 4;
                float4 xv = *(float4*)&xs[r][c + ((c >> 5) << 2)];
                acc[0][q * 4 + 0] += s4.x * xv.x; acc[0][q * 4 + 1] += s4.x * xv.y;
                acc[0][q * 4 + 2] += s4.x * xv.z; acc[0][q * 4 + 3] += s4.x * xv.w;
                acc[1][q * 4 + 0] += s4.y * xv.x; acc[1][q * 4 + 1] += s4.y * xv.y;
                acc[1][q * 4 + 2] += s4.y * xv.z; acc[1][q * 4 + 3] += s4.y * xv.w;
                acc[2][q * 4 + 0] += s4.z * xv.x; acc[2][q * 4 + 1] += s4.z * xv.y;
                acc[2][q * 4 + 2] += s4.z * xv.z; acc[2][q * 4 + 3] += s4.z * xv.w;
                acc[3][q * 4 + 0] += s4.w * xv.x; acc[3][q * 4 + 1] += s4.w * xv.y;
                acc[3][q * 4 + 2] += s4.w * xv.z; acc[3][q * 4 + 3] += s4.w * xv.w;
            }
        }
    }
    float* dst = Spart + (size_t)(b * PB + p) * MM * CC;
#pragma unroll
    for (int mi = 0; mi < 4; ++mi)
#pragma unroll
        for (int q = 0; q < 4; ++q) {
            float4 v = {acc[mi][q * 4 + 0], acc[mi][q * 4 + 1],
                        acc[mi][q * 4 + 2], acc[mi][q * 4 + 3]};
            *(float4*)(dst + (size_t)(m0 + mi) * CC + c0 + q * 4) = v;
        }
}

// ---------- E: edge path: gather SW2 + softmax + transpose reduce ----------
__global__ __launch_bounds__(128, 1) void kE(const float* __restrict__ eattr,
                                             const int* __restrict__ eidx,
                                             const float* __restrict__ sw2,
                                             const float* __restrict__ bes,
                                             float* __restrict__ t1_acc,
                                             float* __restrict__ esn_acc) {
    __shared__ float u[2][64][65];
    __shared__ float eav[2][64];
    __shared__ float redt[2][64], redn[2][64];
    __shared__ float bes_s[64];
    const int tid = threadIdx.x, w = tid >> 6, l = tid & 63;
    const int eg = blockIdx.x * 128 + tid;   // 262144 edges
    const int b = eg >> 16;
    if (tid < 64) bes_s[tid] = bes[tid];
    const int2 idx = ((const int2*)eidx)[eg];
    const float ea = eattr[eg];
    const float4* g0 = (const float4*)(sw2 + (size_t)(b * NN + idx.x) * MM);
    const float4* g1 = (const float4*)(sw2 + (size_t)(b * NN + idx.y) * MM);
    __syncthreads();

    float v[64];
    float mx = -1e30f;
#pragma unroll
    for (int q = 0; q < 16; ++q) {
        float4 aa = g0[q], bb = g1[q];
        v[q * 4 + 0] = aa.x + bb.x + bes_s[q * 4 + 0];
        v[q * 4 + 1] = aa.y + bb.y + bes_s[q * 4 + 1];
        v[q * 4 + 2] = aa.z + bb.z + bes_s[q * 4 + 2];
        v[q * 4 + 3] = aa.w + bb.w + bes_s[q * 4 + 3];
    }
#pragma unroll
    for (int m = 0; m < 64; ++m) mx = fmaxf(mx, v[m]);
    float s = 0.f;
#pragma unroll
    for (int m = 0; m < 64; ++m) { v[m] = __expf(v[m] - mx); s += v[m]; }
    float inv = 1.f / s;
#pragma unroll
    for (int m = 0; m < 64; ++m) u[w][l][m] = v[m] * inv;
    eav[w][l] = ea;
    __syncthreads();

    float tl = 0.f, nl = 0.f;
    for (int r = 0; r < 64; ++r) {
        float e = u[w][r][l];
        nl += e;
        tl += e * eav[w][r];
    }
    redt[w][l] = tl; redn[w][l] = nl;
    __syncthreads();
    if (w == 0) {
        atomicAdd(&t1_acc[b * 64 + l], redt[0][l] + redt[1][l]);
        atomicAdd(&esn_acc[b * 64 + l], redn[0][l] + redn[1][l]);
    }
}

// ---------- F: reduce partials + combine everything -> slice_token ----------
__global__ __launch_bounds__(256) void kF(const float* __restrict__ ws,
                                          const float* __restrict__ Wfx,
                                          const float* __restrict__ bfx,
                                          const float* __restrict__ Wfe,
                                          const float* __restrict__ bfe,
                                          const float* __restrict__ phe,
                                          float* __restrict__ out0,
                                          int PB) {
    __shared__ float srow[256];
    const int bid = blockIdx.x;          // 256 blocks = (b,m)
    const int b = bid >> 6, m = bid & 63;
    const int t = threadIdx.x;
    const float* Sp = ws + WS_SPART;
    float sv = 0.f;
    for (int p = 0; p < PB; ++p)
        sv += Sp[((size_t)(b * PB + p) * MM + m) * CC + t];
    srow[t] = sv;
    __syncthreads();
    float acc = 0.f;
#pragma unroll 4
    for (int k = 0; k < 256; ++k) acc += srow[k] * Wfx[k * CC + t];
    float nv  = ws[WS_NORM + b * 64 + m];
    float t1v = ws[WS_T1   + b * 64 + m];
    float ev  = ws[WS_ESN  + b * 64 + m];
    const float scale = (float)NN / (float)EE;   // 0.25
    float num = acc + nv * bfx[t] + scale * (t1v * Wfe[t] + ev * (bfe[t] + phe[t]));
    float den = nv + scale * ev + 1e-5f;
    out0[(size_t)(b * MM + m) * CC + t] = num / den;
}

extern "C" void kernel_launch(void* const* d_in, const int* in_sizes, int n_in,
                              void* d_out, int out_size, void* d_ws, size_t ws_size,
                              hipStream_t stream) {
    const float* x     = (const float*)d_in[0];
    const float* eattr = (const float*)d_in[1];
    const int*   eidx  = (const int*)d_in[2];
    const float* Wfx   = (const float*)d_in[3];
    const float* bfx   = (const float*)d_in[4];
    const float* Wx    = (const float*)d_in[5];
    const float* bx    = (const float*)d_in[6];
    const float* Wsl   = (const float*)d_in[7];
    const float* bsl   = (const float*)d_in[8];
    const float* tx    = (const float*)d_in[9];
    const float* phx   = (const float*)d_in[10];
    const float* Wfe   = (const float*)d_in[11];
    const float* bfe   = (const float*)d_in[12];
    const float* te    = (const float*)d_in[13];
    const float* Wes   = (const float*)d_in[14];
    const float* bes   = (const float*)d_in[15];
    const float* phe   = (const float*)d_in[16];

    float* out0 = (float*)d_out;                  // slice_token [B,M,C]
    float* out1 = out0 + (size_t)BB * MM * CC;    // slice_weight [B,N,M]
    float* ws   = (float*)d_ws;

    int PB = 128;
    while (PB > 8) {
        size_t need = (size_t)(WS_SPART + (size_t)BB * PB * MM * CC) * sizeof(float);
        if (need <= ws_size) break;
        PB >>= 1;
    }
    int rowsPB = NN / PB;

    hipMemsetAsync(ws, 0, 768 * sizeof(float), stream);

    kP <<<64, 256, 0, stream>>>(Wx, Wsl, ws);
    kP2<<<1, 64, 0, stream>>>(bx, phx, Wsl, bsl, tx, te, Wes, ws);
    kN1<<<256, 256, 0, stream>>>(x, ws, out1, ws + WS_NORM);
    kN3<<<512, 256, 0, stream>>>(out1, ws, ws + WS_SW2);
    kN2<<<BB * PB, 256, 0, stream>>>(x, out1, ws + WS_SPART, PB, rowsPB);
    kE <<<2048, 128, 0, stream>>>(eattr, eidx, ws + WS_SW2, bes,
                                  ws + WS_T1, ws + WS_ESN);
    kF <<<256, 256, 0, stream>>>(ws, Wfx, bfx, Wfe, bfe, phe, out0, PB);
}

// Round 5
// 212.107 us; speedup vs baseline: 1.1313x; 1.1313x over previous
//
#include <hip/hip_runtime.h>

#define BB 4
#define NN 16384
#define EE 65536
#define CC 256
#define MM 64

// ws float offsets
#define WS_NORM   0                  // B*M (atomics, memset each launch)
#define WS_T1     256
#define WS_ESN    512
#define WS_BCOMB  768                // 64
#define WS_ITX    832                // 64
#define WS_ITE    896                // 64
#define WS_WES2   1024               // 64*64 = 4096  (itE ⊙ W_eslice)
#define WS_WCOMB  5120               // C*M = 16384
#define WS_SW2    21504              // B*N*M = 4194304
#define WS_SPART  4215808            // B*PB*M*C partials

// ---------- P: W_comb = W_x @ W_slice ----------
__global__ __launch_bounds__(256) void kP(const float* __restrict__ Wx,
                                          const float* __restrict__ Wsl,
                                          float* __restrict__ ws) {
    int e = blockIdx.x * 256 + threadIdx.x;   // 16384 entries
    int c = e >> 6, m = e & 63;
    float acc = 0.f;
    for (int k = 0; k < CC; ++k) acc += Wx[c * CC + k] * Wsl[k * MM + m];
    ws[WS_WCOMB + e] = acc;
}

// ---------- P2: b_comb, inverse temps, Wes2 = itE ⊙ Wes ----------
__global__ void kP2(const float* __restrict__ bx, const float* __restrict__ phx,
                    const float* __restrict__ Wsl, const float* __restrict__ bsl,
                    const float* __restrict__ tx, const float* __restrict__ te,
                    const float* __restrict__ Wes,
                    float* __restrict__ ws) {
    int m = threadIdx.x; // 64 threads
    float acc = bsl[m];
    for (int k = 0; k < CC; ++k) acc += (bx[k] + phx[k]) * Wsl[k * MM + m];
    ws[WS_BCOMB + m] = acc;
    ws[WS_ITX + m] = 1.f / fminf(fmaxf(tx[m], 0.01f), 5.f);
    ws[WS_ITE + m] = 1.f / fminf(fmaxf(te[m], 0.01f), 5.f);
    for (int k = 0; k < 64; ++k) {
        float itk = 1.f / fminf(fmaxf(te[k], 0.01f), 5.f);
        ws[WS_WES2 + k * 64 + m] = itk * Wes[k * 64 + m];
    }
}

// ---------- N1: logits = x@W_comb + b_comb, softmax -> slice_weight + norm ----------
// 512 blocks x 256 threads; 128 rows/block; thread owns 2 rows x 16 m.
// r4: grid was 256 blocks = 1 block/CU = 4 waves/CU -> occupancy 10%, VALUBusy 17%,
// and per-thread state (104 floats incl. prefetch regs) overflowed 72 VGPRs into
// scratch (84MB extra WRITE_SIZE). Fix: acc[2][16]=32 regs, no prefetch regs,
// 512 blocks (2 blocks/CU, 8 waves/CU).
__global__ __launch_bounds__(256, 2) void kN1(const float* __restrict__ x,
                                              const float* __restrict__ ws,
                                              float* __restrict__ out1,
                                              float* __restrict__ norm_acc) {
    __shared__ float xs[128 * 36];   // 18 KB, row stride 36 (2-way conflicts = free)
    __shared__ float Wst[32 * 64];   // 8 KB  (one 32-row chunk of W_comb)
    __shared__ float redn[4][64];
    __shared__ float bcs[64], itxs[64];
    const int tid = threadIdx.x;
    const int row0 = blockIdx.x * 128;
    const int b = blockIdx.x >> 7;   // 128 blocks per batch
    const int r = tid >> 2;          // 0..63 (rows r and r+64)
    const int h = tid & 3;           // m-quarter
    const float* Wc = ws + WS_WCOMB;

    if (tid < 64) { bcs[tid] = ws[WS_BCOMB + tid]; itxs[tid] = ws[WS_ITX + tid]; }

    float acc[2][16];
#pragma unroll
    for (int i = 0; i < 2; ++i)
#pragma unroll
        for (int j = 0; j < 16; ++j) acc[i][j] = 0.f;

    for (int c0 = 0; c0 < CC; c0 += 32) {
        __syncthreads();
        // stage x[row0..row0+127][c0..c0+31]: 1024 float4, 4 per thread
#pragma unroll
        for (int i = 0; i < 4; ++i) {
            int flat = i * 256 + tid, rr = flat >> 3, cb = (flat & 7) * 4;
            float4 v = *(const float4*)(x + (size_t)(row0 + rr) * CC + c0 + cb);
            *(float4*)&xs[rr * 36 + cb] = v;
        }
        // stage W chunk [32][64]: 512 float4, 2 per thread
#pragma unroll
        for (int i = 0; i < 2; ++i) {
            int f4 = i * 256 + tid;
            *(float4*)&Wst[f4 * 4] = *(const float4*)(Wc + c0 * MM + f4 * 4);
        }
        __syncthreads();
#pragma unroll 4
        for (int cc = 0; cc < 32; ++cc) {
            float xv0 = xs[(r     ) * 36 + cc];
            float xv1 = xs[(r + 64) * 36 + cc];
            const float4* wrow = (const float4*)&Wst[cc * 64 + h * 16];
#pragma unroll
            for (int q = 0; q < 4; ++q) {
                float4 w = wrow[q];
                acc[0][q * 4 + 0] += xv0 * w.x; acc[0][q * 4 + 1] += xv0 * w.y;
                acc[0][q * 4 + 2] += xv0 * w.z; acc[0][q * 4 + 3] += xv0 * w.w;
                acc[1][q * 4 + 0] += xv1 * w.x; acc[1][q * 4 + 1] += xv1 * w.y;
                acc[1][q * 4 + 2] += xv1 * w.z; acc[1][q * 4 + 3] += xv1 * w.w;
            }
        }
    }

    // softmax per row (quad h=0..3 shares each row)
    float colsum[16];
#pragma unroll
    for (int j = 0; j < 16; ++j) colsum[j] = 0.f;
#pragma unroll
    for (int i = 0; i < 2; ++i) {
        float mx = -1e30f;
#pragma unroll
        for (int j = 0; j < 16; ++j) {
            int m = h * 16 + j;
            acc[i][j] = (acc[i][j] + bcs[m]) * itxs[m];
            mx = fmaxf(mx, acc[i][j]);
        }
        mx = fmaxf(mx, __shfl_xor(mx, 1));
        mx = fmaxf(mx, __shfl_xor(mx, 2));
        float s = 0.f;
#pragma unroll
        for (int j = 0; j < 16; ++j) { acc[i][j] = __expf(acc[i][j] - mx); s += acc[i][j]; }
        s += __shfl_xor(s, 1);
        s += __shfl_xor(s, 2);
        float inv = 1.f / s;
        int row = row0 + r + 64 * i;
#pragma unroll
        for (int q = 0; q < 4; ++q) {
            float4 v = {acc[i][q * 4 + 0] * inv, acc[i][q * 4 + 1] * inv,
                        acc[i][q * 4 + 2] * inv, acc[i][q * 4 + 3] * inv};
            *(float4*)(out1 + (size_t)row * MM + h * 16 + q * 4) = v;
#pragma unroll
            for (int j = 0; j < 4; ++j) colsum[q * 4 + j] += ((float*)&v)[j];
        }
    }
    // reduce colsum across the 16 r-lanes of each wave
#pragma unroll
    for (int j = 0; j < 16; ++j) {
        colsum[j] += __shfl_xor(colsum[j], 4);
        colsum[j] += __shfl_xor(colsum[j], 8);
        colsum[j] += __shfl_xor(colsum[j], 16);
        colsum[j] += __shfl_xor(colsum[j], 32);
    }
    int w = tid >> 6;
    if ((tid & 63) < 4) {
#pragma unroll
        for (int j = 0; j < 16; ++j) redn[w][h * 16 + j] = colsum[j];
    }
    __syncthreads();
    if (tid < 64)
        atomicAdd(&norm_acc[b * MM + tid],
                  redn[0][tid] + redn[1][tid] + redn[2][tid] + redn[3][tid]);
}

// ---------- N3: SW2 = sw @ Wes2  ([B*N,64]@[64,64]) ----------
__global__ __launch_bounds__(256, 1) void kN3(const float* __restrict__ sw,
                                              const float* __restrict__ ws,
                                              float* __restrict__ sw2) {
    __shared__ float Wst[64 * 64]; // 16 KB
    const int tid = threadIdx.x;
    const int r = tid >> 1, h = tid & 1;
    const size_t row = (size_t)blockIdx.x * 128 + r;
#pragma unroll
    for (int i = 0; i < 4; ++i) {
        int f4 = i * 256 + tid;
        *(float4*)&Wst[f4 * 4] = *(const float4*)(ws + WS_WES2 + f4 * 4);
    }
    float u[64];
    const float4* rp = (const float4*)(sw + row * MM);
#pragma unroll
    for (int q = 0; q < 16; ++q) {
        float4 a = rp[q];
        u[q * 4 + 0] = a.x; u[q * 4 + 1] = a.y; u[q * 4 + 2] = a.z; u[q * 4 + 3] = a.w;
    }
    float acc[32];
#pragma unroll
    for (int j = 0; j < 32; ++j) acc[j] = 0.f;
    __syncthreads();
#pragma unroll
    for (int k = 0; k < 64; ++k) {
        float uk = u[k];
        const float4* wr4 = (const float4*)&Wst[k * 64 + h * 32];
#pragma unroll
        for (int q = 0; q < 8; ++q) {
            float4 wv = wr4[q];
            acc[q * 4 + 0] += uk * wv.x; acc[q * 4 + 1] += uk * wv.y;
            acc[q * 4 + 2] += uk * wv.z; acc[q * 4 + 3] += uk * wv.w;
        }
    }
#pragma unroll
    for (int q = 0; q < 8; ++q) {
        float4 v = {acc[q * 4 + 0], acc[q * 4 + 1], acc[q * 4 + 2], acc[q * 4 + 3]};
        *(float4*)(sw2 + row * MM + h * 32 + q * 4) = v;
    }
}

// ---------- N2: Spart[b][p] = sw_chunk^T @ x_chunk (register-tiled) ----------
__global__ __launch_bounds__(256, 1) void kN2(const float* __restrict__ x,
                                              const float* __restrict__ sw,
                                              float* __restrict__ Spart,
                                              int PB, int rowsPB) {
    __shared__ float xs[32][288];   // 36 KB, col j stored at j + (j>>5)*4
    __shared__ float sws[32][64];   // 8 KB
    const int bid = blockIdx.x;
    const int b = bid / PB, p = bid % PB;
    const int base = b * NN + p * rowsPB;
    const int tid = threadIdx.x;
    const int tm = tid >> 4, tc = tid & 15;
    const int m0 = tm * 4, c0 = tc * 16;

    float acc[4][16];
#pragma unroll
    for (int mi = 0; mi < 4; ++mi)
#pragma unroll
        for (int j = 0; j < 16; ++j) acc[mi][j] = 0.f;

    for (int r0 = 0; r0 < rowsPB; r0 += 32) {
        __syncthreads();
#pragma unroll
        for (int i = 0; i < 8; ++i) {
            int flat = i * 256 + tid;
            int r = flat >> 6, c = (flat & 63) * 4;
            float4 v = *(const float4*)(x + (size_t)(base + r0 + r) * CC + c);
            *(float4*)&xs[r][c + ((c >> 5) << 2)] = v;
        }
#pragma unroll
        for (int i = 0; i < 2; ++i) {
            int flat = i * 256 + tid;
            int r = flat >> 4, c = (flat & 15) * 4;
            *(float4*)&sws[r][c] = *(const float4*)(sw + (size_t)(base + r0 + r) * MM + c);
        }
        __syncthreads();
#pragma unroll 2
        for (int r = 0; r < 32; ++r) {
            float4 s4 = *(float4*)&sws[r][m0];
#pragma unroll
            for (int q = 0; q < 4; ++q) {
                int c = c0 + q * 4;
                float4 xv = *(float4*)&xs[r][c + ((c >> 5) << 2)];
                acc[0][q * 4 + 0] += s4.x * xv.x; acc[0][q * 4 + 1] += s4.x * xv.y;
                acc[0][q * 4 + 2] += s4.x * xv.z; acc[0][q * 4 + 3] += s4.x * xv.w;
                acc[1][q * 4 + 0] += s4.y * xv.x; acc[1][q * 4 + 1] += s4.y * xv.y;
                acc[1][q * 4 + 2] += s4.y * xv.z; acc[1][q * 4 + 3] += s4.y * xv.w;
                acc[2][q * 4 + 0] += s4.z * xv.x; acc[2][q * 4 + 1] += s4.z * xv.y;
                acc[2][q * 4 + 2] += s4.z * xv.z; acc[2][q * 4 + 3] += s4.z * xv.w;
                acc[3][q * 4 + 0] += s4.w * xv.x; acc[3][q * 4 + 1] += s4.w * xv.y;
                acc[3][q * 4 + 2] += s4.w * xv.z; acc[3][q * 4 + 3] += s4.w * xv.w;
            }
        }
    }
    float* dst = Spart + (size_t)(b * PB + p) * MM * CC;
#pragma unroll
    for (int mi = 0; mi < 4; ++mi)
#pragma unroll
        for (int q = 0; q < 4; ++q) {
            float4 v = {acc[mi][q * 4 + 0], acc[mi][q * 4 + 1],
                        acc[mi][q * 4 + 2], acc[mi][q * 4 + 3]};
            *(float4*)(dst + (size_t)(m0 + mi) * CC + c0 + q * 4) = v;
        }
}

// ---------- E: edge path: gather SW2 + softmax + transpose reduce ----------
__global__ __launch_bounds__(128, 1) void kE(const float* __restrict__ eattr,
                                             const int* __restrict__ eidx,
                                             const float* __restrict__ sw2,
                                             const float* __restrict__ bes,
                                             float* __restrict__ t1_acc,
                                             float* __restrict__ esn_acc) {
    __shared__ float u[2][64][65];
    __shared__ float eav[2][64];
    __shared__ float redt[2][64], redn[2][64];
    __shared__ float bes_s[64];
    const int tid = threadIdx.x, w = tid >> 6, l = tid & 63;
    const int eg = blockIdx.x * 128 + tid;   // 262144 edges
    const int b = eg >> 16;
    if (tid < 64) bes_s[tid] = bes[tid];
    const int2 idx = ((const int2*)eidx)[eg];
    const float ea = eattr[eg];
    const float4* g0 = (const float4*)(sw2 + (size_t)(b * NN + idx.x) * MM);
    const float4* g1 = (const float4*)(sw2 + (size_t)(b * NN + idx.y) * MM);
    __syncthreads();

    float v[64];
    float mx = -1e30f;
#pragma unroll
    for (int q = 0; q < 16; ++q) {
        float4 aa = g0[q], bb = g1[q];
        v[q * 4 + 0] = aa.x + bb.x + bes_s[q * 4 + 0];
        v[q * 4 + 1] = aa.y + bb.y + bes_s[q * 4 + 1];
        v[q * 4 + 2] = aa.z + bb.z + bes_s[q * 4 + 2];
        v[q * 4 + 3] = aa.w + bb.w + bes_s[q * 4 + 3];
    }
#pragma unroll
    for (int m = 0; m < 64; ++m) mx = fmaxf(mx, v[m]);
    float s = 0.f;
#pragma unroll
    for (int m = 0; m < 64; ++m) { v[m] = __expf(v[m] - mx); s += v[m]; }
    float inv = 1.f / s;
#pragma unroll
    for (int m = 0; m < 64; ++m) u[w][l][m] = v[m] * inv;
    eav[w][l] = ea;
    __syncthreads();

    float tl = 0.f, nl = 0.f;
    for (int r = 0; r < 64; ++r) {
        float e = u[w][r][l];
        nl += e;
        tl += e * eav[w][r];
    }
    redt[w][l] = tl; redn[w][l] = nl;
    __syncthreads();
    if (w == 0) {
        atomicAdd(&t1_acc[b * 64 + l], redt[0][l] + redt[1][l]);
        atomicAdd(&esn_acc[b * 64 + l], redn[0][l] + redn[1][l]);
    }
}

// ---------- F: reduce partials + combine everything -> slice_token ----------
__global__ __launch_bounds__(256) void kF(const float* __restrict__ ws,
                                          const float* __restrict__ Wfx,
                                          const float* __restrict__ bfx,
                                          const float* __restrict__ Wfe,
                                          const float* __restrict__ bfe,
                                          const float* __restrict__ phe,
                                          float* __restrict__ out0,
                                          int PB) {
    __shared__ float srow[256];
    const int bid = blockIdx.x;          // 256 blocks = (b,m)
    const int b = bid >> 6, m = bid & 63;
    const int t = threadIdx.x;
    const float* Sp = ws + WS_SPART;
    float sv = 0.f;
    for (int p = 0; p < PB; ++p)
        sv += Sp[((size_t)(b * PB + p) * MM + m) * CC + t];
    srow[t] = sv;
    __syncthreads();
    float acc = 0.f;
#pragma unroll 4
    for (int k = 0; k < 256; ++k) acc += srow[k] * Wfx[k * CC + t];
    float nv  = ws[WS_NORM + b * 64 + m];
    float t1v = ws[WS_T1   + b * 64 + m];
    float ev  = ws[WS_ESN  + b * 64 + m];
    const float scale = (float)NN / (float)EE;   // 0.25
    float num = acc + nv * bfx[t] + scale * (t1v * Wfe[t] + ev * (bfe[t] + phe[t]));
    float den = nv + scale * ev + 1e-5f;
    out0[(size_t)(b * MM + m) * CC + t] = num / den;
}

extern "C" void kernel_launch(void* const* d_in, const int* in_sizes, int n_in,
                              void* d_out, int out_size, void* d_ws, size_t ws_size,
                              hipStream_t stream) {
    const float* x     = (const float*)d_in[0];
    const float* eattr = (const float*)d_in[1];
    const int*   eidx  = (const int*)d_in[2];
    const float* Wfx   = (const float*)d_in[3];
    const float* bfx   = (const float*)d_in[4];
    const float* Wx    = (const float*)d_in[5];
    const float* bx    = (const float*)d_in[6];
    const float* Wsl   = (const float*)d_in[7];
    const float* bsl   = (const float*)d_in[8];
    const float* tx    = (const float*)d_in[9];
    const float* phx   = (const float*)d_in[10];
    const float* Wfe   = (const float*)d_in[11];
    const float* bfe   = (const float*)d_in[12];
    const float* te    = (const float*)d_in[13];
    const float* Wes   = (const float*)d_in[14];
    const float* bes   = (const float*)d_in[15];
    const float* phe   = (const float*)d_in[16];

    float* out0 = (float*)d_out;                  // slice_token [B,M,C]
    float* out1 = out0 + (size_t)BB * MM * CC;    // slice_weight [B,N,M]
    float* ws   = (float*)d_ws;

    int PB = 128;
    while (PB > 8) {
        size_t need = (size_t)(WS_SPART + (size_t)BB * PB * MM * CC) * sizeof(float);
        if (need <= ws_size) break;
        PB >>= 1;
    }
    int rowsPB = NN / PB;

    hipMemsetAsync(ws, 0, 768 * sizeof(float), stream);

    kP <<<64, 256, 0, stream>>>(Wx, Wsl, ws);
    kP2<<<1, 64, 0, stream>>>(bx, phx, Wsl, bsl, tx, te, Wes, ws);
    kN1<<<512, 256, 0, stream>>>(x, ws, out1, ws + WS_NORM);
    kN3<<<512, 256, 0, stream>>>(out1, ws, ws + WS_SW2);
    kN2<<<BB * PB, 256, 0, stream>>>(x, out1, ws + WS_SPART, PB, rowsPB);
    kE <<<2048, 128, 0, stream>>>(eattr, eidx, ws + WS_SW2, bes,
                                  ws + WS_T1, ws + WS_ESN);
    kF <<<256, 256, 0, stream>>>(ws, Wfx, bfx, Wfe, bfe, phe, out0, PB);
}

// Round 6
// 187.466 us; speedup vs baseline: 1.2799x; 1.1314x over previous
//
#include <hip/hip_runtime.h>

#define BB 4
#define NN 16384
#define EE 65536
#define CC 256
#define MM 64

// ws float offsets
#define WS_NORM   0                  // B*M (atomics, memset each launch)
#define WS_T1     256
#define WS_ESN    512
#define WS_BCOMB  768                // 64
#define WS_ITX    832                // 64
#define WS_ITE    896                // 64
#define WS_WES2   1024               // 64*64 = 4096  (itE ⊙ W_eslice)
#define WS_WCOMB  5120               // C*M = 16384
#define WS_SW2    21504              // B*N*M = 4194304 (dead after kE; Ssum overlays it)
#define WS_SSUM   WS_SW2             // B*M*C = 262144 (written by kR after kE)
#define WS_SPART  4215808            // B*PB*M*C partials

// ---------- P: W_comb = W_x @ W_slice ----------
__global__ __launch_bounds__(256) void kP(const float* __restrict__ Wx,
                                          const float* __restrict__ Wsl,
                                          float* __restrict__ ws) {
    int e = blockIdx.x * 256 + threadIdx.x;   // 16384 entries
    int c = e >> 6, m = e & 63;
    float acc = 0.f;
    for (int k = 0; k < CC; ++k) acc += Wx[c * CC + k] * Wsl[k * MM + m];
    ws[WS_WCOMB + e] = acc;
}

// ---------- P2: b_comb, inverse temps, Wes2 = itE ⊙ Wes ----------
__global__ void kP2(const float* __restrict__ bx, const float* __restrict__ phx,
                    const float* __restrict__ Wsl, const float* __restrict__ bsl,
                    const float* __restrict__ tx, const float* __restrict__ te,
                    const float* __restrict__ Wes,
                    float* __restrict__ ws) {
    int m = threadIdx.x; // 64 threads
    float acc = bsl[m];
    for (int k = 0; k < CC; ++k) acc += (bx[k] + phx[k]) * Wsl[k * MM + m];
    ws[WS_BCOMB + m] = acc;
    ws[WS_ITX + m] = 1.f / fminf(fmaxf(tx[m], 0.01f), 5.f);
    ws[WS_ITE + m] = 1.f / fminf(fmaxf(te[m], 0.01f), 5.f);
    for (int k = 0; k < 64; ++k) {
        float itk = 1.f / fminf(fmaxf(te[k], 0.01f), 5.f);
        ws[WS_WES2 + k * 64 + m] = itk * Wes[k * 64 + m];
    }
}

// ---------- N1: logits = x@W_comb + b_comb, softmax -> slice_weight + norm ----------
// 512 blocks x 256 threads; 128 rows/block; thread owns 2 rows x 16 m.
__global__ __launch_bounds__(256, 2) void kN1(const float* __restrict__ x,
                                              const float* __restrict__ ws,
                                              float* __restrict__ out1,
                                              float* __restrict__ norm_acc) {
    __shared__ float xs[128 * 36];   // 18 KB
    __shared__ float Wst[32 * 64];   // 8 KB
    __shared__ float redn[4][64];
    __shared__ float bcs[64], itxs[64];
    const int tid = threadIdx.x;
    const int row0 = blockIdx.x * 128;
    const int b = blockIdx.x >> 7;   // 128 blocks per batch
    const int r = tid >> 2;          // 0..63 (rows r and r+64)
    const int h = tid & 3;           // m-quarter
    const float* Wc = ws + WS_WCOMB;

    if (tid < 64) { bcs[tid] = ws[WS_BCOMB + tid]; itxs[tid] = ws[WS_ITX + tid]; }

    float acc[2][16];
#pragma unroll
    for (int i = 0; i < 2; ++i)
#pragma unroll
        for (int j = 0; j < 16; ++j) acc[i][j] = 0.f;

    for (int c0 = 0; c0 < CC; c0 += 32) {
        __syncthreads();
#pragma unroll
        for (int i = 0; i < 4; ++i) {
            int flat = i * 256 + tid, rr = flat >> 3, cb = (flat & 7) * 4;
            float4 v = *(const float4*)(x + (size_t)(row0 + rr) * CC + c0 + cb);
            *(float4*)&xs[rr * 36 + cb] = v;
        }
#pragma unroll
        for (int i = 0; i < 2; ++i) {
            int f4 = i * 256 + tid;
            *(float4*)&Wst[f4 * 4] = *(const float4*)(Wc + c0 * MM + f4 * 4);
        }
        __syncthreads();
#pragma unroll 4
        for (int cc = 0; cc < 32; ++cc) {
            float xv0 = xs[(r     ) * 36 + cc];
            float xv1 = xs[(r + 64) * 36 + cc];
            const float4* wrow = (const float4*)&Wst[cc * 64 + h * 16];
#pragma unroll
            for (int q = 0; q < 4; ++q) {
                float4 w = wrow[q];
                acc[0][q * 4 + 0] += xv0 * w.x; acc[0][q * 4 + 1] += xv0 * w.y;
                acc[0][q * 4 + 2] += xv0 * w.z; acc[0][q * 4 + 3] += xv0 * w.w;
                acc[1][q * 4 + 0] += xv1 * w.x; acc[1][q * 4 + 1] += xv1 * w.y;
                acc[1][q * 4 + 2] += xv1 * w.z; acc[1][q * 4 + 3] += xv1 * w.w;
            }
        }
    }

    float colsum[16];
#pragma unroll
    for (int j = 0; j < 16; ++j) colsum[j] = 0.f;
#pragma unroll
    for (int i = 0; i < 2; ++i) {
        float mx = -1e30f;
#pragma unroll
        for (int j = 0; j < 16; ++j) {
            int m = h * 16 + j;
            acc[i][j] = (acc[i][j] + bcs[m]) * itxs[m];
            mx = fmaxf(mx, acc[i][j]);
        }
        mx = fmaxf(mx, __shfl_xor(mx, 1));
        mx = fmaxf(mx, __shfl_xor(mx, 2));
        float s = 0.f;
#pragma unroll
        for (int j = 0; j < 16; ++j) { acc[i][j] = __expf(acc[i][j] - mx); s += acc[i][j]; }
        s += __shfl_xor(s, 1);
        s += __shfl_xor(s, 2);
        float inv = 1.f / s;
        int row = row0 + r + 64 * i;
#pragma unroll
        for (int q = 0; q < 4; ++q) {
            float4 v = {acc[i][q * 4 + 0] * inv, acc[i][q * 4 + 1] * inv,
                        acc[i][q * 4 + 2] * inv, acc[i][q * 4 + 3] * inv};
            *(float4*)(out1 + (size_t)row * MM + h * 16 + q * 4) = v;
#pragma unroll
            for (int j = 0; j < 4; ++j) colsum[q * 4 + j] += ((float*)&v)[j];
        }
    }
#pragma unroll
    for (int j = 0; j < 16; ++j) {
        colsum[j] += __shfl_xor(colsum[j], 4);
        colsum[j] += __shfl_xor(colsum[j], 8);
        colsum[j] += __shfl_xor(colsum[j], 16);
        colsum[j] += __shfl_xor(colsum[j], 32);
    }
    int w = tid >> 6;
    if ((tid & 63) < 4) {
#pragma unroll
        for (int j = 0; j < 16; ++j) redn[w][h * 16 + j] = colsum[j];
    }
    __syncthreads();
    if (tid < 64)
        atomicAdd(&norm_acc[b * MM + tid],
                  redn[0][tid] + redn[1][tid] + redn[2][tid] + redn[3][tid]);
}

// ---------- N3: SW2 = sw @ Wes2  ([B*N,64]@[64,64]) ----------
__global__ __launch_bounds__(256, 1) void kN3(const float* __restrict__ sw,
                                              const float* __restrict__ ws,
                                              float* __restrict__ sw2) {
    __shared__ float Wst[64 * 64]; // 16 KB
    const int tid = threadIdx.x;
    const int r = tid >> 1, h = tid & 1;
    const size_t row = (size_t)blockIdx.x * 128 + r;
#pragma unroll
    for (int i = 0; i < 4; ++i) {
        int f4 = i * 256 + tid;
        *(float4*)&Wst[f4 * 4] = *(const float4*)(ws + WS_WES2 + f4 * 4);
    }
    float u[64];
    const float4* rp = (const float4*)(sw + row * MM);
#pragma unroll
    for (int q = 0; q < 16; ++q) {
        float4 a = rp[q];
        u[q * 4 + 0] = a.x; u[q * 4 + 1] = a.y; u[q * 4 + 2] = a.z; u[q * 4 + 3] = a.w;
    }
    float acc[32];
#pragma unroll
    for (int j = 0; j < 32; ++j) acc[j] = 0.f;
    __syncthreads();
#pragma unroll
    for (int k = 0; k < 64; ++k) {
        float uk = u[k];
        const float4* wr4 = (const float4*)&Wst[k * 64 + h * 32];
#pragma unroll
        for (int q = 0; q < 8; ++q) {
            float4 wv = wr4[q];
            acc[q * 4 + 0] += uk * wv.x; acc[q * 4 + 1] += uk * wv.y;
            acc[q * 4 + 2] += uk * wv.z; acc[q * 4 + 3] += uk * wv.w;
        }
    }
#pragma unroll
    for (int q = 0; q < 8; ++q) {
        float4 v = {acc[q * 4 + 0], acc[q * 4 + 1], acc[q * 4 + 2], acc[q * 4 + 3]};
        *(float4*)(sw2 + row * MM + h * 32 + q * 4) = v;
    }
}

// ---------- N2: Spart = sw_chunk^T @ x_chunk, C-split (512 blocks) ----------
// r5: 256 blocks = 1 block/CU left kN2 with 4 waves/CU. C-split: each block
// handles 128 of 256 columns -> 512 blocks, 2/CU, 8 waves/CU; LDS 26 KB.
__global__ __launch_bounds__(256, 2) void kN2(const float* __restrict__ x,
                                              const float* __restrict__ sw,
                                              float* __restrict__ Spart,
                                              int PB, int rowsPB) {
    __shared__ float xs[32][144];   // 18 KB, col j at j + (j>>5)*4 (2-way = free)
    __shared__ float sws[32][64];   // 8 KB
    const int bid = blockIdx.x;
    const int ch = bid & 1;
    const int p = (bid >> 1) % PB, b = (bid >> 1) / PB;
    const int base = b * NN + p * rowsPB;
    const int tid = threadIdx.x;
    const int tm = tid >> 4, tc = tid & 15;
    const int m0 = tm * 4;
    const int c0 = tc * 8;          // local col within the 128-wide half

    float acc[4][8];
#pragma unroll
    for (int mi = 0; mi < 4; ++mi)
#pragma unroll
        for (int j = 0; j < 8; ++j) acc[mi][j] = 0.f;

    for (int r0 = 0; r0 < rowsPB; r0 += 32) {
        __syncthreads();
        // stage x half-rows: 32 rows x 32 float4
#pragma unroll
        for (int i = 0; i < 4; ++i) {
            int flat = i * 256 + tid;
            int r = flat >> 5, c = (flat & 31) * 4;
            float4 v = *(const float4*)(x + (size_t)(base + r0 + r) * CC + ch * 128 + c);
            *(float4*)&xs[r][c + ((c >> 5) << 2)] = v;
        }
        // stage sw: 32 rows x 16 float4
#pragma unroll
        for (int i = 0; i < 2; ++i) {
            int flat = i * 256 + tid;
            int r = flat >> 4, c = (flat & 15) * 4;
            *(float4*)&sws[r][c] = *(const float4*)(sw + (size_t)(base + r0 + r) * MM + c);
        }
        __syncthreads();
#pragma unroll 2
        for (int r = 0; r < 32; ++r) {
            float4 s4 = *(float4*)&sws[r][m0];
#pragma unroll
            for (int q = 0; q < 2; ++q) {
                int c = c0 + q * 4;
                float4 xv = *(float4*)&xs[r][c + ((c >> 5) << 2)];
                acc[0][q * 4 + 0] += s4.x * xv.x; acc[0][q * 4 + 1] += s4.x * xv.y;
                acc[0][q * 4 + 2] += s4.x * xv.z; acc[0][q * 4 + 3] += s4.x * xv.w;
                acc[1][q * 4 + 0] += s4.y * xv.x; acc[1][q * 4 + 1] += s4.y * xv.y;
                acc[1][q * 4 + 2] += s4.y * xv.z; acc[1][q * 4 + 3] += s4.y * xv.w;
                acc[2][q * 4 + 0] += s4.z * xv.x; acc[2][q * 4 + 1] += s4.z * xv.y;
                acc[2][q * 4 + 2] += s4.z * xv.z; acc[2][q * 4 + 3] += s4.z * xv.w;
                acc[3][q * 4 + 0] += s4.w * xv.x; acc[3][q * 4 + 1] += s4.w * xv.y;
                acc[3][q * 4 + 2] += s4.w * xv.z; acc[3][q * 4 + 3] += s4.w * xv.w;
            }
        }
    }
    float* dst = Spart + (size_t)(b * PB + p) * MM * CC + ch * 128;
#pragma unroll
    for (int mi = 0; mi < 4; ++mi)
#pragma unroll
        for (int q = 0; q < 2; ++q) {
            float4 v = {acc[mi][q * 4 + 0], acc[mi][q * 4 + 1],
                        acc[mi][q * 4 + 2], acc[mi][q * 4 + 3]};
            *(float4*)(dst + (size_t)(m0 + mi) * CC + c0 + q * 4) = v;
        }
}

// ---------- E: edge path: gather SW2 + softmax + transpose reduce ----------
__global__ __launch_bounds__(128, 1) void kE(const float* __restrict__ eattr,
                                             const int* __restrict__ eidx,
                                             const float* __restrict__ sw2,
                                             const float* __restrict__ bes,
                                             float* __restrict__ t1_acc,
                                             float* __restrict__ esn_acc) {
    __shared__ float u[2][64][65];
    __shared__ float eav[2][64];
    __shared__ float redt[2][64], redn[2][64];
    __shared__ float bes_s[64];
    const int tid = threadIdx.x, w = tid >> 6, l = tid & 63;
    const int eg = blockIdx.x * 128 + tid;   // 262144 edges
    const int b = eg >> 16;
    if (tid < 64) bes_s[tid] = bes[tid];
    const int2 idx = ((const int2*)eidx)[eg];
    const float ea = eattr[eg];
    const float4* g0 = (const float4*)(sw2 + (size_t)(b * NN + idx.x) * MM);
    const float4* g1 = (const float4*)(sw2 + (size_t)(b * NN + idx.y) * MM);
    __syncthreads();

    float v[64];
    float mx = -1e30f;
#pragma unroll
    for (int q = 0; q < 16; ++q) {
        float4 aa = g0[q], bb = g1[q];
        v[q * 4 + 0] = aa.x + bb.x + bes_s[q * 4 + 0];
        v[q * 4 + 1] = aa.y + bb.y + bes_s[q * 4 + 1];
        v[q * 4 + 2] = aa.z + bb.z + bes_s[q * 4 + 2];
        v[q * 4 + 3] = aa.w + bb.w + bes_s[q * 4 + 3];
    }
#pragma unroll
    for (int m = 0; m < 64; ++m) mx = fmaxf(mx, v[m]);
    float s = 0.f;
#pragma unroll
    for (int m = 0; m < 64; ++m) { v[m] = __expf(v[m] - mx); s += v[m]; }
    float inv = 1.f / s;
#pragma unroll
    for (int m = 0; m < 64; ++m) u[w][l][m] = v[m] * inv;
    eav[w][l] = ea;
    __syncthreads();

    float tl = 0.f, nl = 0.f;
    for (int r = 0; r < 64; ++r) {
        float e = u[w][r][l];
        nl += e;
        tl += e * eav[w][r];
    }
    redt[w][l] = tl; redn[w][l] = nl;
    __syncthreads();
    if (w == 0) {
        atomicAdd(&t1_acc[b * 64 + l], redt[0][l] + redt[1][l]);
        atomicAdd(&esn_acc[b * 64 + l], redn[0][l] + redn[1][l]);
    }
}

// ---------- R: parallel partial reduce Spart -> Ssum [B,M,C] ----------
// r5: the old fused kF read 17MB of partials at 310 GB/s (1 block/CU,
// latency-bound) = 55us. 1024 blocks / 16 waves per CU stream it at BW.
__global__ __launch_bounds__(256) void kR(const float* __restrict__ Spart,
                                          float* __restrict__ Ssum, int PB) {
    const int idx = blockIdx.x * 256 + threadIdx.x;  // B*M*C = 262144
    const int b = idx >> 14;                          // M*C = 16384 per b
    const int mc = idx & 16383;
    const float* sp = Spart + (size_t)b * PB * MM * CC + mc;
    float a0 = 0.f, a1 = 0.f, a2 = 0.f, a3 = 0.f;
    for (int p = 0; p < PB; p += 4) {
        a0 += sp[(size_t)(p + 0) * MM * CC];
        a1 += sp[(size_t)(p + 1) * MM * CC];
        a2 += sp[(size_t)(p + 2) * MM * CC];
        a3 += sp[(size_t)(p + 3) * MM * CC];
    }
    Ssum[idx] = (a0 + a1) + (a2 + a3);
}

// ---------- F2: matvec + combine -> slice_token ----------
__global__ __launch_bounds__(256) void kF2(const float* __restrict__ ws,
                                           const float* __restrict__ Wfx,
                                           const float* __restrict__ bfx,
                                           const float* __restrict__ Wfe,
                                           const float* __restrict__ bfe,
                                           const float* __restrict__ phe,
                                           float* __restrict__ out0) {
    __shared__ float srow[256];
    const int bid = blockIdx.x;          // 256 blocks = (b,m)
    const int b = bid >> 6, m = bid & 63;
    const int t = threadIdx.x;
    srow[t] = ws[WS_SSUM + (size_t)(b * MM + m) * CC + t];
    __syncthreads();
    float acc = 0.f;
#pragma unroll 8
    for (int k = 0; k < 256; ++k) acc += srow[k] * Wfx[k * CC + t];
    float nv  = ws[WS_NORM + b * 64 + m];
    float t1v = ws[WS_T1   + b * 64 + m];
    float ev  = ws[WS_ESN  + b * 64 + m];
    const float scale = (float)NN / (float)EE;   // 0.25
    float num = acc + nv * bfx[t] + scale * (t1v * Wfe[t] + ev * (bfe[t] + phe[t]));
    float den = nv + scale * ev + 1e-5f;
    out0[(size_t)(b * MM + m) * CC + t] = num / den;
}

extern "C" void kernel_launch(void* const* d_in, const int* in_sizes, int n_in,
                              void* d_out, int out_size, void* d_ws, size_t ws_size,
                              hipStream_t stream) {
    const float* x     = (const float*)d_in[0];
    const float* eattr = (const float*)d_in[1];
    const int*   eidx  = (const int*)d_in[2];
    const float* Wfx   = (const float*)d_in[3];
    const float* bfx   = (const float*)d_in[4];
    const float* Wx    = (const float*)d_in[5];
    const float* bx    = (const float*)d_in[6];
    const float* Wsl   = (const float*)d_in[7];
    const float* bsl   = (const float*)d_in[8];
    const float* tx    = (const float*)d_in[9];
    const float* phx   = (const float*)d_in[10];
    const float* Wfe   = (const float*)d_in[11];
    const float* bfe   = (const float*)d_in[12];
    const float* te    = (const float*)d_in[13];
    const float* Wes   = (const float*)d_in[14];
    const float* bes   = (const float*)d_in[15];
    const float* phe   = (const float*)d_in[16];

    float* out0 = (float*)d_out;                  // slice_token [B,M,C]
    float* out1 = out0 + (size_t)BB * MM * CC;    // slice_weight [B,N,M]
    float* ws   = (float*)d_ws;

    int PB = 64;
    while (PB > 8) {
        size_t need = (size_t)(WS_SPART + (size_t)BB * PB * MM * CC) * sizeof(float);
        if (need <= ws_size) break;
        PB >>= 1;
    }
    int rowsPB = NN / PB;

    hipMemsetAsync(ws, 0, 768 * sizeof(float), stream);

    kP <<<64, 256, 0, stream>>>(Wx, Wsl, ws);
    kP2<<<1, 64, 0, stream>>>(bx, phx, Wsl, bsl, tx, te, Wes, ws);
    kN1<<<512, 256, 0, stream>>>(x, ws, out1, ws + WS_NORM);
    kN3<<<512, 256, 0, stream>>>(out1, ws, ws + WS_SW2);
    kE <<<2048, 128, 0, stream>>>(eattr, eidx, ws + WS_SW2, bes,
                                  ws + WS_T1, ws + WS_ESN);
    kN2<<<BB * PB * 2, 256, 0, stream>>>(x, out1, ws + WS_SPART, PB, rowsPB);
    kR <<<1024, 256, 0, stream>>>(ws + WS_SPART, ws + WS_SSUM, PB);
    kF2<<<256, 256, 0, stream>>>(ws, Wfx, bfx, Wfe, bfe, phe, out0);
}